// Round 1
// 60.844 us; speedup vs baseline: 1.0062x; 1.0062x over previous
//
#include <hip/hip_runtime.h>

#define NQ 15

// RY([[c,-s],[s,c]]) on window bit T (T in 1..3) of the 16-dim half-state.
template<int T>
__device__ inline void apply_ry16(float (&re)[16], float (&im)[16], float cg, float sg) {
#pragma unroll
    for (int x = 0; x < 16; x++) {
        if (!(x & (1 << T))) {
            const int y = x | (1 << T);
            float r0 = re[x], i0 = im[x], r1 = re[y], i1 = im[y];
            re[x] = cg * r0 - sg * r1;
            im[x] = cg * i0 - sg * i1;
            re[y] = sg * r0 + cg * r1;
            im[y] = sg * i0 + cg * i1;
        }
    }
}

// Lane layout within a wave: lane = e*32 + h*16 + q
//   e (bit 5): batch sub-element (2 per wave)
//   h (bit 4): which half of window-bit-4 (qubit q+2) this lane owns
//   q (bits 0..3): qubit index; q==15 is the zero-angle identity slot
__global__ __launch_bounds__(256)
void HybridRegression_lightcone3_kernel(const float* __restrict__ sb,    // (B,15)
                                        const float* __restrict__ theta, // (45,)
                                        const float* __restrict__ hw,    // (1,15)
                                        const float* __restrict__ hb,    // (1,)
                                        float* __restrict__ out,         // (B,)
                                        int batch) {
    const int wave = threadIdx.x >> 6;
    const int lane = threadIdx.x & 63;
    const int e = lane >> 5;
    const int h = (lane >> 4) & 1;
    const int q = lane & 15;

    int b = blockIdx.x * 8 + wave * 2 + e;
    const bool bv = (b < batch);
    if (!bv) b = batch - 1;              // clamp for safe loads; store is guarded
    const bool qv = (q < NQ);

    // Own angles (zero outside range -> identity factors; q==15 holds identity)
    const float a  = qv ? sb[b * NQ + q]    : 0.0f;
    const float t1 = qv ? theta[q]          : 0.0f;
    const float t2 = qv ? theta[NQ + q]     : 0.0f;
    const float t3 = qv ? theta[2 * NQ + q] : 0.0f;

    float sh, ch;  sincosf(0.5f * a,  &sh, &ch);
    float s1, c1;  sincosf(0.5f * t1, &s1, &c1);
    float s2, c2;  sincosf(0.5f * t2, &s2, &c2);
    float s3, c3;  sincosf(t3,        &s3, &c3);  // FULL angle: fused into measurement

    // Combined RX(a)·RY(t1)|0> per-qubit factor: (x0+i y0)|0> + (x1+i y1)|1>
    const float x0 = c1 * ch, y0 = s1 * sh;
    const float x1 = s1 * ch, y1 = -c1 * sh;

    // Gather window factors (qubits q-2..q+2) from same-(e,h) neighbor lanes.
    const int grp = lane & 48;
    float fx0[5], fy0[5], fx1[5], fy1[5];
#pragma unroll
    for (int w = 0; w < 5; w++) {
        const int j = q - 2 + w;
        const int src = grp | ((j >= 0 && j < NQ) ? j : NQ);
        fx0[w] = __shfl(x0, src, 64);
        fy0[w] = __shfl(y0, src, 64);
        fx1[w] = __shfl(x1, src, 64);
        fy1[w] = __shfl(y1, src, 64);
    }
    float g2c[3], g2s[3];
#pragma unroll
    for (int w = 0; w < 3; w++) {
        const int j = q - 1 + w;
        const int src = grp | ((j >= 0 && j < NQ) ? j : NQ);
        g2c[w] = __shfl(c2, src, 64);
        g2s[w] = __shfl(s2, src, 64);
    }

    // Build the 4-qubit product over window bits 0..3 (qubits q-2..q+1).
    float re[16], im[16];
    re[0] = fx0[0]; im[0] = fy0[0];
    re[1] = fx1[0]; im[1] = fy1[0];
#pragma unroll
    for (int w = 1; w < 4; w++) {
#pragma unroll
        for (int x = 0; x < 8; x++) {
            if (x < (1 << w)) {
                const int y = x + (1 << w);
                const float r = re[x], i = im[x];
                re[y] = r * fx1[w] - i * fy1[w];
                im[y] = r * fy1[w] + i * fx1[w];
                re[x] = r * fx0[w] - i * fy0[w];
                im[x] = r * fy0[w] + i * fx0[w];
            }
        }
    }
    // Window bit 4 (qubit q+2): this lane owns half h of it.
    const float gx = h ? fx1[4] : fx0[4];
    const float gy = h ? fy1[4] : fy0[4];
#pragma unroll
    for (int x = 0; x < 16; x++) {
        const float r = re[x], i = im[x];
        re[x] = r * gx - i * gy;
        im[x] = r * gy + i * gx;
    }

    // Layer-1 CZ chain (b0,b1)(b1,b2)(b2,b3)(b3,b4); b4 == h.
#pragma unroll
    for (int x = 0; x < 16; x++) {
        const int p = (((x >> 0) & 3) == 3) + (((x >> 1) & 3) == 3)
                    + (((x >> 2) & 3) == 3);
        if (p & 1) { re[x] = -re[x]; im[x] = -im[x]; }
    }
    if (h) {   // (b3,b4) sign: negate bit3-set amps on the h==1 half
#pragma unroll
        for (int x = 8; x < 16; x++) { re[x] = -re[x]; im[x] = -im[x]; }
    }

    // Layer-2 RY on window bits 1..3 (qubits q-1..q+1) — fully lane-local now.
    apply_ry16<1>(re, im, g2c[0], g2s[0]);
    apply_ry16<2>(re, im, g2c[1], g2s[1]);
    apply_ry16<3>(re, im, g2c[2], g2s[2]);

    // Layer-2 CZ (1,2)(2,3), folded.
#pragma unroll
    for (int x = 0; x < 16; x++) {
        const int p = (((x >> 1) & 3) == 3) + (((x >> 2) & 3) == 3);
        if (p & 1) { re[x] = -re[x]; im[x] = -im[x]; }
    }

    // Fused layer-3 RY(t3) + <Z> on bit 2 (partial over this lane's 16 amps):
    //   zq = cos(t3) * sum(p0 - p1)  -  sin(t3) * 2 * sum Re(a0 * conj(a1))
    float zd = 0.0f, zc = 0.0f;
#pragma unroll
    for (int x = 0; x < 16; x++) {
        if (!(x & 4)) {
            const int y = x | 4;
            zd += (re[x] * re[x] + im[x] * im[x]) - (re[y] * re[y] + im[y] * im[y]);
            zc += re[x] * re[y] + im[x] * im[y];
        }
    }
    // Linear in (zd, zc), so each half-lane contributes its partial directly.
    float contrib = qv ? hw[(NQ - 1) - q] * (c3 * zd - 2.0f * s3 * zc) : 0.0f;

    // Butterfly reduction within the 32-lane same-e group (sums both h halves
    // and all qubits; lanes with q>=15 contribute 0).
#pragma unroll
    for (int off = 16; off >= 1; off >>= 1)
        contrib += __shfl_xor(contrib, off, 64);

    if ((lane & 31) == 0 && bv)
        out[b] = contrib + hb[0];
}

extern "C" void kernel_launch(void* const* d_in, const int* in_sizes, int n_in,
                              void* d_out, int out_size, void* d_ws, size_t ws_size,
                              hipStream_t stream) {
    const float* sb    = (const float*)d_in[0]; // state_batch (512,15)
    const float* theta = (const float*)d_in[1]; // (45,)
    const float* hw    = (const float*)d_in[2]; // (1,15)
    const float* hb    = (const float*)d_in[3]; // (1,)
    float* out = (float*)d_out;                 // (512,) fp32

    const int batch = in_sizes[0] / NQ;
    const int blocks = (batch + 7) / 8;         // 4 waves * 2 elems per block

    hipLaunchKernelGGL(HybridRegression_lightcone3_kernel,
                       dim3(blocks), dim3(256), 0, stream,
                       sb, theta, hw, hb, out, batch);
}